// Round 2
// baseline (273.161 us; speedup 1.0000x reference)
//
#include <hip/hip_runtime.h>
#include <hip/hip_bf16.h>
#include <stdint.h>

// SlidingWindowAttention: x[4,4096,1024] f32, Wqkv[3072,1024] f32, Wproj[1024,1024] f32
// I/O is float32; internal pipeline is bf16 (MFMA) with f32 accum.
// qkv = x@Wqkv^T (q*=0.125 fused) -> per (b,h) flattened-window attention
// (256x256 over Df=1024) -> out = attn_out @ Wproj^T (f32 out).

using u16 = unsigned short;
typedef __attribute__((ext_vector_type(4))) float f32x4;
typedef __attribute__((ext_vector_type(8))) short s16x8;

#define MFMA_BF16(a, b, c) __builtin_amdgcn_mfma_f32_16x16x32_bf16((a), (b), (c), 0, 0, 0)

__device__ __forceinline__ u16 f2bf(float f) {
  union { float f; uint32_t u; } v; v.f = f;
  uint32_t r = v.u + 0x7fffu + ((v.u >> 16) & 1u);  // RNE
  return (u16)(r >> 16);
}

// async global->LDS, 16B per lane; LDS dest is wave-uniform base + lane*16
__device__ __forceinline__ void gld16(const void* g, void* l) {
  auto gp = (const __attribute__((address_space(1))) void*)(uintptr_t)g;
  auto lp = (__attribute__((address_space(3))) void*)(uint32_t)(uintptr_t)l;
  __builtin_amdgcn_global_load_lds(gp, lp, 16, 0, 0);
}

// ---------------------------------------------------------------------------
// f32 -> bf16 convert, 8 elems/thread/iter (32B in, 16B out)
// ---------------------------------------------------------------------------
__global__ __launch_bounds__(256) void cvt_bf16(const float* __restrict__ in,
                                                u16* __restrict__ out, int n8) {
  for (int i = blockIdx.x * blockDim.x + threadIdx.x; i < n8;
       i += gridDim.x * blockDim.x) {
    const float4* p = (const float4*)in + (size_t)i * 2;
    float4 a = p[0], b = p[1];
    s16x8 r;
    r[0] = (short)f2bf(a.x); r[1] = (short)f2bf(a.y);
    r[2] = (short)f2bf(a.z); r[3] = (short)f2bf(a.w);
    r[4] = (short)f2bf(b.x); r[5] = (short)f2bf(b.y);
    r[6] = (short)f2bf(b.z); r[7] = (short)f2bf(b.w);
    *(s16x8*)(out + (size_t)i * 8) = r;
  }
}

// ---------------------------------------------------------------------------
// GEMM C[M,N] = A[M,K=1024] * W[N,K]^T, bf16 in, f32 accum.
// 128x128 tile, 4 waves (2x2), each wave 64x64 via 4x4 x mfma_16x16x32_bf16.
// QS: scale cols < 1024 by 0.125. F32OUT: write f32 (else bf16).
// ---------------------------------------------------------------------------
template <bool QS, bool F32OUT>
__global__ __launch_bounds__(256) void gemm_bt(const u16* __restrict__ A,
                                               const u16* __restrict__ W,
                                               void* __restrict__ C, int N) {
  __shared__ alignas(16) u16 lA[128 * 32];
  __shared__ alignas(16) u16 lB[128 * 32];
  const int tid = threadIdx.x;
  const int wv = tid >> 6, lane = tid & 63;
  const int fr = lane & 15, fg = lane >> 4;   // frag row / k-group
  const int li = lane >> 2, lc = lane & 3;    // staging row / 16B-chunk
  const int bm = blockIdx.x, bn = blockIdx.y;
  const int wm = wv >> 1, wn = wv & 1;

  const f32x4 fz = {0.f, 0.f, 0.f, 0.f};
  f32x4 acc[4][4];
#pragma unroll
  for (int i = 0; i < 4; ++i)
#pragma unroll
    for (int j = 0; j < 4; ++j) acc[i][j] = fz;

  const u16* Ab = A + (size_t)bm * 128 * 1024 + (size_t)lc * 8;
  const u16* Wb = W + (size_t)bn * 128 * 1024 + (size_t)lc * 8;

  for (int kt = 0; kt < 32; ++kt) {
    const int k0 = kt * 32;
#pragma unroll
    for (int j = 0; j < 2; ++j) {
      const int q = wv * 2 + j;  // wave-uniform
      gld16(Ab + (size_t)(q * 16 + li) * 1024 + k0, lA + q * 512);
      gld16(Wb + (size_t)(q * 16 + li) * 1024 + k0, lB + q * 512);
    }
    __syncthreads();
    s16x8 af[4], bfv[4];
#pragma unroll
    for (int mi = 0; mi < 4; ++mi)
      af[mi] = *(const s16x8*)(lA + (wm * 64 + mi * 16 + fr) * 32 + fg * 8);
#pragma unroll
    for (int ni = 0; ni < 4; ++ni)
      bfv[ni] = *(const s16x8*)(lB + (wn * 64 + ni * 16 + fr) * 32 + fg * 8);
#pragma unroll
    for (int ni = 0; ni < 4; ++ni)
#pragma unroll
      for (int mi = 0; mi < 4; ++mi)
        acc[mi][ni] = MFMA_BF16(af[mi], bfv[ni], acc[mi][ni]);
    __syncthreads();
  }

  const float scale = (QS && bn < 8) ? 0.125f : 1.0f;
#pragma unroll
  for (int mi = 0; mi < 4; ++mi)
#pragma unroll
    for (int ni = 0; ni < 4; ++ni) {
      const int row = bm * 128 + wm * 64 + mi * 16 + fg * 4;
      const int col = bn * 128 + wn * 64 + ni * 16 + fr;
      if (F32OUT) {
        float* cp = (float*)C + (size_t)row * N + col;
#pragma unroll
        for (int r = 0; r < 4; ++r) cp[(size_t)r * N] = acc[mi][ni][r] * scale;
      } else {
        u16* cp = (u16*)C + (size_t)row * N + col;
#pragma unroll
        for (int r = 0; r < 4; ++r) cp[(size_t)r * N] = f2bf(acc[mi][ni][r] * scale);
      }
    }
}

// ---------------------------------------------------------------------------
// Windowed attention. Grid = 256 blocks, 256 threads (4 waves).
// Block -> (b,h, qb): qb = 64-row slice of the 256 window-rows.
// XCD swizzle: the 4 qb-blocks of one (b,h) share an XCD for K/V L2 reuse.
// Per (b,h): Q,K,V are [256 rows][Df=1024]; row w, col d=(p*64+e) lives at
// qkv[(b*4096 + w*16 + p)*3072 + s*1024 + h*64 + e], s in {0,1,2}.
// ---------------------------------------------------------------------------
__global__ __launch_bounds__(256) void attn_win(const u16* __restrict__ qkv,
                                                u16* __restrict__ attn) {
  const int bid = blockIdx.x;
  const int bh = (bid & 7) + ((bid >> 5) << 3);  // same bh -> same XCD (bid%8)
  const int qb = (bid >> 3) & 3;
  const int b = bh >> 4, h = bh & 15;

  const int tid = threadIdx.x;
  const int wv = tid >> 6, lane = tid & 63;
  const int fr = lane & 15, fg = lane >> 4;
  const int li = lane >> 2, lc = lane & 3;

  __shared__ alignas(16) char smem[33792 + 20480];
  u16* lP = (u16*)smem;                      // [64][264] bf16 P (persist ph2->ph3)
  u16* lQ = (u16*)(smem + 33792);            // [64][32]
  u16* lK = (u16*)(smem + 33792 + 4096);     // [256][32]
  float* redm = (float*)(smem + 33792);          // [4][64]
  float* reds = (float*)(smem + 33792 + 1024);   // [4][64]
  u16* lVt = (u16*)(smem + 33792);           // [256 n][40] V^T tile (32 x + pad)

  const size_t qbase = (size_t)b * 4096 * 3072;

  const f32x4 fz = {0.f, 0.f, 0.f, 0.f};
  f32x4 acc[4][4];
#pragma unroll
  for (int i = 0; i < 4; ++i)
#pragma unroll
    for (int j = 0; j < 4; ++j) acc[i][j] = fz;

  // ---- phase 1: S = Q K^T  (wave wv owns cols wv*64..+64, all 64 rows)
  for (int kt = 0; kt < 32; ++kt) {
    const size_t dofs = (size_t)(kt >> 1) * 3072 + h * 64 + (kt & 1) * 32 + lc * 8;
    {
      const int r = wv * 16 + li;  // q-row 0..63
      gld16(qkv + qbase + (size_t)((qb * 64 + r) * 16) * 3072 + dofs, lQ + wv * 512);
    }
#pragma unroll
    for (int j = 0; j < 4; ++j) {
      const int q = wv * 4 + j;
      const int r = q * 16 + li;  // k-row 0..255
      gld16(qkv + qbase + (size_t)(r * 16) * 3072 + 1024 + dofs, lK + q * 512);
    }
    __syncthreads();
    s16x8 qa[4];
#pragma unroll
    for (int mi = 0; mi < 4; ++mi)
      qa[mi] = *(const s16x8*)(lQ + (mi * 16 + fr) * 32 + fg * 8);
#pragma unroll
    for (int ni = 0; ni < 4; ++ni) {
      s16x8 kb = *(const s16x8*)(lK + (wv * 64 + ni * 16 + fr) * 32 + fg * 8);
#pragma unroll
      for (int mi = 0; mi < 4; ++mi)
        acc[mi][ni] = MFMA_BF16(qa[mi], kb, acc[mi][ni]);
    }
    __syncthreads();
  }

  // ---- phase 2: softmax over 256 cols; rows per lane: mi*16 + fg*4 + r
  float rmax[4][4], rnrm[4][4];
#pragma unroll
  for (int mi = 0; mi < 4; ++mi)
#pragma unroll
    for (int r = 0; r < 4; ++r) {
      float m = fmaxf(fmaxf(acc[mi][0][r], acc[mi][1][r]),
                      fmaxf(acc[mi][2][r], acc[mi][3][r]));
      for (int o = 1; o < 16; o <<= 1) m = fmaxf(m, __shfl_xor(m, o));
      rmax[mi][r] = m;
    }
  if (fr == 0) {
#pragma unroll
    for (int mi = 0; mi < 4; ++mi)
#pragma unroll
      for (int r = 0; r < 4; ++r) redm[wv * 64 + mi * 16 + fg * 4 + r] = rmax[mi][r];
  }
  __syncthreads();
#pragma unroll
  for (int mi = 0; mi < 4; ++mi)
#pragma unroll
    for (int r = 0; r < 4; ++r) {
      const int row = mi * 16 + fg * 4 + r;
      rmax[mi][r] = fmaxf(fmaxf(redm[row], redm[64 + row]),
                          fmaxf(redm[128 + row], redm[192 + row]));
    }
#pragma unroll
  for (int mi = 0; mi < 4; ++mi)
#pragma unroll
    for (int r = 0; r < 4; ++r) {
      float s = 0.f;
#pragma unroll
      for (int ni = 0; ni < 4; ++ni) {
        float p = exp2f((acc[mi][ni][r] - rmax[mi][r]) * 1.4426950408889634f);
        acc[mi][ni][r] = p;
        s += p;
      }
      for (int o = 1; o < 16; o <<= 1) s += __shfl_xor(s, o);
      rnrm[mi][r] = s;
    }
  if (fr == 0) {
#pragma unroll
    for (int mi = 0; mi < 4; ++mi)
#pragma unroll
      for (int r = 0; r < 4; ++r) reds[wv * 64 + mi * 16 + fg * 4 + r] = rnrm[mi][r];
  }
  __syncthreads();
#pragma unroll
  for (int mi = 0; mi < 4; ++mi)
#pragma unroll
    for (int r = 0; r < 4; ++r) {
      const int row = mi * 16 + fg * 4 + r;
      rnrm[mi][r] = 1.f / (reds[row] + reds[64 + row] + reds[128 + row] + reds[192 + row]);
    }
#pragma unroll
  for (int mi = 0; mi < 4; ++mi)
#pragma unroll
    for (int ni = 0; ni < 4; ++ni)
#pragma unroll
      for (int r = 0; r < 4; ++r)
        lP[(mi * 16 + fg * 4 + r) * 264 + wv * 64 + ni * 16 + fr] =
            f2bf(acc[mi][ni][r] * rnrm[mi][r]);
  __syncthreads();  // lP ready; redm/reds region freed for lVt

  // ---- phase 3: O = P V, n-chunks of 256 cols, k(x)-tiles of 32
#pragma unroll 1
  for (int nc = 0; nc < 4; ++nc) {
    f32x4 oacc[4][4];
#pragma unroll
    for (int i = 0; i < 4; ++i)
#pragma unroll
      for (int j = 0; j < 4; ++j) oacc[i][j] = fz;
#pragma unroll 1
    for (int xt = 0; xt < 8; ++xt) {
      // stage V^T tile: [32 x][256 n] -> lVt[n][40] (x at 0..31, pad to 40)
#pragma unroll
      for (int it = 0; it < 4; ++it) {
        const int id = it * 256 + tid;
        const int xl = id & 31, ng = id >> 5;
        const int d = nc * 256 + ng * 8;
        const u16* g = qkv + qbase +
                       (size_t)((xt * 32 + xl) * 16 + (d >> 6)) * 3072 + 2048 +
                       h * 64 + (d & 63);
        s16x8 v = *(const s16x8*)g;
#pragma unroll
        for (int i = 0; i < 8; ++i) lVt[(ng * 8 + i) * 40 + xl] = (u16)v[i];
      }
      __syncthreads();
      s16x8 pa[4];
#pragma unroll
      for (int mi = 0; mi < 4; ++mi)
        pa[mi] = *(const s16x8*)(lP + (mi * 16 + fr) * 264 + xt * 32 + fg * 8);
#pragma unroll
      for (int ni = 0; ni < 4; ++ni) {
        s16x8 vb = *(const s16x8*)(lVt + (wv * 64 + ni * 16 + fr) * 40 + fg * 8);
#pragma unroll
        for (int mi = 0; mi < 4; ++mi)
          oacc[mi][ni] = MFMA_BF16(pa[mi], vb, oacc[mi][ni]);
      }
      __syncthreads();
    }
    // store O chunk -> attn_out token layout [B,N,H*hd]
#pragma unroll
    for (int mi = 0; mi < 4; ++mi)
#pragma unroll
      for (int ni = 0; ni < 4; ++ni) {
        const int row = mi * 16 + fg * 4;
        const int d = nc * 256 + wv * 64 + ni * 16 + fr;
        const int p = d >> 6, e = d & 63;
        const size_t base =
            (size_t)(b * 4096 + (qb * 64 + row) * 16 + p) * 1024 + h * 64 + e;
#pragma unroll
        for (int r = 0; r < 4; ++r)
          attn[base + (size_t)r * 16 * 1024] = f2bf(oacc[mi][ni][r]);
      }
  }
}

// ---------------------------------------------------------------------------
extern "C" void kernel_launch(void* const* d_in, const int* in_sizes, int n_in,
                              void* d_out, int out_size, void* d_ws, size_t ws_size,
                              hipStream_t stream) {
  (void)in_sizes; (void)n_in; (void)out_size; (void)ws_size;
  const float* x = (const float*)d_in[0];      // [16384,1024] f32
  const float* wqkv = (const float*)d_in[1];   // [3072,1024] f32
  const float* wproj = (const float*)d_in[2];  // [1024,1024] f32
  float* out = (float*)d_out;                  // [16384,1024] f32

  char* ws = (char*)d_ws;
  u16* qkv = (u16*)ws;                          // [16384,3072] bf16 (100.7 MB)
  u16* xbf = (u16*)(ws + 100663296);            // [16384,1024] bf16 (33.6 MB)
  u16* attn = xbf;                              // reuse: xbf dead after gemm1
  u16* wqkvb = (u16*)(ws + 134217728);          // [3072,1024] bf16 (6.3 MB)
  u16* wprojb = (u16*)(ws + 140509184);         // [1024,1024] bf16 (2.1 MB)

  cvt_bf16<<<2048, 256, 0, stream>>>(x, xbf, 16777216 / 8);
  cvt_bf16<<<1536, 256, 0, stream>>>(wqkv, wqkvb, 3145728 / 8);
  cvt_bf16<<<512, 256, 0, stream>>>(wproj, wprojb, 1048576 / 8);

  gemm_bt<true, false><<<dim3(128, 24), 256, 0, stream>>>(xbf, wqkvb, qkv, 3072);
  attn_win<<<256, 256, 0, stream>>>(qkv, attn);
  gemm_bt<false, true><<<dim3(128, 8), 256, 0, stream>>>(attn, wprojb, out, 1024);
}

// Round 3
// 245.375 us; speedup vs baseline: 1.1132x; 1.1132x over previous
//
#include <hip/hip_runtime.h>
#include <hip/hip_bf16.h>
#include <stdint.h>

// SlidingWindowAttention: x[4,4096,1024] f32, Wqkv[3072,1024] f32, Wproj[1024,1024] f32
// I/O f32; internal bf16 (MFMA) with f32 accum.
// qkv = x@Wqkv^T (q*=0.125 fused) -> per (b,h) flattened-window attention
// (256x256 over Df=1024) -> out = attn_out @ Wproj^T (f32 out).

using u16 = unsigned short;
typedef __attribute__((ext_vector_type(4))) float f32x4;
typedef __attribute__((ext_vector_type(8))) short s16x8;

#define MFMA_BF16(a, b, c) __builtin_amdgcn_mfma_f32_16x16x32_bf16((a), (b), (c), 0, 0, 0)

__device__ __forceinline__ u16 f2bf(float f) {
  union { float f; uint32_t u; } v; v.f = f;
  uint32_t r = v.u + 0x7fffu + ((v.u >> 16) & 1u);  // RNE
  return (u16)(r >> 16);
}

// async global->LDS, 16B per lane; LDS dest is wave-uniform base + lane*16
__device__ __forceinline__ void gld16(const void* g, void* l) {
  auto gp = (const __attribute__((address_space(1))) void*)(uintptr_t)g;
  auto lp = (__attribute__((address_space(3))) void*)(uint32_t)(uintptr_t)l;
  __builtin_amdgcn_global_load_lds(gp, lp, 16, 0, 0);
}

// ---------------------------------------------------------------------------
// f32 -> bf16 convert, 8 elems/thread/iter (32B in, 16B out)
// ---------------------------------------------------------------------------
__global__ __launch_bounds__(256) void cvt_bf16(const float* __restrict__ in,
                                                u16* __restrict__ out, int n8) {
  for (int i = blockIdx.x * blockDim.x + threadIdx.x; i < n8;
       i += gridDim.x * blockDim.x) {
    const float4* p = (const float4*)in + (size_t)i * 2;
    float4 a = p[0], b = p[1];
    s16x8 r;
    r[0] = (short)f2bf(a.x); r[1] = (short)f2bf(a.y);
    r[2] = (short)f2bf(a.z); r[3] = (short)f2bf(a.w);
    r[4] = (short)f2bf(b.x); r[5] = (short)f2bf(b.y);
    r[6] = (short)f2bf(b.z); r[7] = (short)f2bf(b.w);
    *(s16x8*)(out + (size_t)i * 8) = r;
  }
}

// ---------------------------------------------------------------------------
// 256x256-tile GEMM C[M,N] = A[M,1024] * W[N,1024]^T, bf16 in, f32 accum.
// 512 thr = 8 waves (2M x 4N), per-wave 128x64 out = 8x4 frags of 16x16x32.
// BK=32, triple-buffered LDS (96 KiB), staged 2 K-tiles ahead, counted vmcnt
// (T3+T4), LDS XOR-swizzle on k-granule (T2), setprio around MFMA (T5),
// XCD-chunked block swizzle (T1).
// LDS per buffer: A[256 rows][32k] then B[256 rows][32k], row = 32 u16 = 4
// granules of 16B; element (row,kg) stored at granule (row, kg ^ ((row>>1)&3)).
// Store side is linear (global_load_lds), so the global SOURCE is inverse-
// swizzled per rule #21.
// ---------------------------------------------------------------------------
template <bool QS, bool F32OUT, int GN>
__global__ __launch_bounds__(512, 2) void gemm256(const u16* __restrict__ A,
                                                  const u16* __restrict__ W,
                                                  void* __restrict__ C) {
  __shared__ alignas(16) u16 lds[3 * 16384];
  const int tid = threadIdx.x;
  const int wv = tid >> 6, lane = tid & 63;
  const int fr = lane & 15, fg = lane >> 4;
  const int wm = wv >> 2, wn = wv & 3;
  const int N = GN * 256;

  // T1: XCD-chunked swizzle (nwg % 8 == 0), bm-major logical order
  const int nwg = 64 * GN;
  const int p = blockIdx.x;
  const int logical = (p & 7) * (nwg >> 3) + (p >> 3);
  const int bm = logical / GN, bn = logical % GN;

  // staging constants: thread covers (row = j*128 + tid>>2, granule tid&3)
  const int srow = tid >> 2;
  const int skg = (tid & 3) ^ ((tid >> 3) & 3);  // inverse swizzle on source

  const u16* As = A + (size_t)(bm * 256 + srow) * 1024 + skg * 8;
  const u16* Ws = W + (size_t)(bn * 256 + srow) * 1024 + skg * 8;

  const f32x4 fz = {0.f, 0.f, 0.f, 0.f};
  f32x4 acc[8][4];
#pragma unroll
  for (int i = 0; i < 8; ++i)
#pragma unroll
    for (int j = 0; j < 4; ++j) acc[i][j] = fz;

  auto STAGE = [&](int t) {
    u16* dst = lds + (t % 3) * 16384;
    const int k0 = t * 32;
    gld16(As + k0,              dst + wv * 512);            // A rows 0..127
    gld16(As + 131072 + k0,     dst + 4096 + wv * 512);     // A rows 128..255
    gld16(Ws + k0,              dst + 8192 + wv * 512);     // B rows 0..127
    gld16(Ws + 131072 + k0,     dst + 12288 + wv * 512);    // B rows 128..255
  };

  STAGE(0);
  STAGE(1);

  // swizzled read granule: fg ^ ((fr>>1)&3)  (row bits below 16 cancel)
  const int rsw = (fg ^ ((fr >> 1) & 3)) * 8;
  const int aoff = (wm * 128 + fr) * 32 + rsw;
  const int boff = 8192 + (wn * 64 + fr) * 32 + rsw;

  for (int t = 0; t < 32; ++t) {
    if (t < 30) {
      STAGE(t + 2);
      asm volatile("s_waitcnt vmcnt(8)" ::: "memory");   // tile t landed; t+1,t+2 in flight
    } else if (t == 30) {
      asm volatile("s_waitcnt vmcnt(4)" ::: "memory");
    } else {
      asm volatile("s_waitcnt vmcnt(0)" ::: "memory");
    }
    __builtin_amdgcn_s_barrier();  // all waves' tile-t loads visible

    const u16* buf = lds + (t % 3) * 16384;
    s16x8 af[8], bfv[4];
#pragma unroll
    for (int mi = 0; mi < 4; ++mi)
      af[mi] = *(const s16x8*)(buf + aoff + mi * 512);
#pragma unroll
    for (int ni = 0; ni < 4; ++ni)
      bfv[ni] = *(const s16x8*)(buf + boff + ni * 512);
#pragma unroll
    for (int mi = 4; mi < 8; ++mi)
      af[mi] = *(const s16x8*)(buf + aoff + mi * 512);

    asm volatile("s_waitcnt lgkmcnt(4)" ::: "memory");  // first 8 reads done
    __builtin_amdgcn_sched_barrier(0);
    __builtin_amdgcn_s_setprio(1);
#pragma unroll
    for (int ni = 0; ni < 4; ++ni)
#pragma unroll
      for (int mi = 0; mi < 4; ++mi)
        acc[mi][ni] = MFMA_BF16(af[mi], bfv[ni], acc[mi][ni]);
    __builtin_amdgcn_s_setprio(0);

    asm volatile("s_waitcnt lgkmcnt(0)" ::: "memory");
    __builtin_amdgcn_sched_barrier(0);
    __builtin_amdgcn_s_setprio(1);
#pragma unroll
    for (int ni = 0; ni < 4; ++ni)
#pragma unroll
      for (int mi = 4; mi < 8; ++mi)
        acc[mi][ni] = MFMA_BF16(af[mi], bfv[ni], acc[mi][ni]);
    __builtin_amdgcn_s_setprio(0);
    __builtin_amdgcn_s_barrier();  // all waves done reading buf[t%3]
  }

  const float scale = (QS && bn < 4) ? 0.125f : 1.0f;
#pragma unroll
  for (int mi = 0; mi < 8; ++mi)
#pragma unroll
    for (int ni = 0; ni < 4; ++ni) {
      const int row = bm * 256 + wm * 128 + mi * 16 + fg * 4;
      const int col = bn * 256 + wn * 64 + ni * 16 + fr;
      if (F32OUT) {
        float* cp = (float*)C + (size_t)row * N + col;
#pragma unroll
        for (int r = 0; r < 4; ++r) cp[(size_t)r * N] = acc[mi][ni][r] * scale;
      } else {
        u16* cp = (u16*)C + (size_t)row * N + col;
#pragma unroll
        for (int r = 0; r < 4; ++r) cp[(size_t)r * N] = f2bf(acc[mi][ni][r] * scale);
      }
    }
}

// ---------------------------------------------------------------------------
// Windowed attention. Grid = 256 blocks, 256 threads (4 waves).
// Block -> (b,h, qb): qb = 64-row slice of the 256 window-rows.
// Per (b,h): Q,K,V are [256 rows][Df=1024]; row w, col d=(p*64+e) lives at
// qkv[(b*4096 + w*16 + p)*3072 + s*1024 + h*64 + e], s in {0,1,2}.
// ---------------------------------------------------------------------------
__global__ __launch_bounds__(256) void attn_win(const u16* __restrict__ qkv,
                                                u16* __restrict__ attn) {
  const int bid = blockIdx.x;
  const int bh = (bid & 7) + ((bid >> 5) << 3);  // same bh -> same XCD (bid%8)
  const int qb = (bid >> 3) & 3;
  const int b = bh >> 4, h = bh & 15;

  const int tid = threadIdx.x;
  const int wv = tid >> 6, lane = tid & 63;
  const int fr = lane & 15, fg = lane >> 4;
  const int li = lane >> 2, lc = lane & 3;

  __shared__ alignas(16) char smem[33792 + 20480];
  u16* lP = (u16*)smem;                      // [64][264] bf16 P (persist ph2->ph3)
  u16* lQ = (u16*)(smem + 33792);            // [64][32]
  u16* lK = (u16*)(smem + 33792 + 4096);     // [256][32]
  float* redm = (float*)(smem + 33792);          // [4][64]
  float* reds = (float*)(smem + 33792 + 1024);   // [4][64]
  u16* lVt = (u16*)(smem + 33792);           // [256 n][40] V^T tile (32 x + pad)

  const size_t qbase = (size_t)b * 4096 * 3072;

  const f32x4 fz = {0.f, 0.f, 0.f, 0.f};
  f32x4 acc[4][4];
#pragma unroll
  for (int i = 0; i < 4; ++i)
#pragma unroll
    for (int j = 0; j < 4; ++j) acc[i][j] = fz;

  // ---- phase 1: S = Q K^T  (wave wv owns cols wv*64..+64, all 64 rows)
  for (int kt = 0; kt < 32; ++kt) {
    const size_t dofs = (size_t)(kt >> 1) * 3072 + h * 64 + (kt & 1) * 32 + lc * 8;
    {
      const int r = wv * 16 + li;  // q-row 0..63
      gld16(qkv + qbase + (size_t)((qb * 64 + r) * 16) * 3072 + dofs, lQ + wv * 512);
    }
#pragma unroll
    for (int j = 0; j < 4; ++j) {
      const int q = wv * 4 + j;
      const int r = q * 16 + li;  // k-row 0..255
      gld16(qkv + qbase + (size_t)(r * 16) * 3072 + 1024 + dofs, lK + q * 512);
    }
    __syncthreads();
    s16x8 qa[4];
#pragma unroll
    for (int mi = 0; mi < 4; ++mi)
      qa[mi] = *(const s16x8*)(lQ + (mi * 16 + fr) * 32 + fg * 8);
#pragma unroll
    for (int ni = 0; ni < 4; ++ni) {
      s16x8 kb = *(const s16x8*)(lK + (wv * 64 + ni * 16 + fr) * 32 + fg * 8);
#pragma unroll
      for (int mi = 0; mi < 4; ++mi)
        acc[mi][ni] = MFMA_BF16(qa[mi], kb, acc[mi][ni]);
    }
    __syncthreads();
  }

  // ---- phase 2: softmax over 256 cols; rows per lane: mi*16 + fg*4 + r
  float rmax[4][4], rnrm[4][4];
#pragma unroll
  for (int mi = 0; mi < 4; ++mi)
#pragma unroll
    for (int r = 0; r < 4; ++r) {
      float m = fmaxf(fmaxf(acc[mi][0][r], acc[mi][1][r]),
                      fmaxf(acc[mi][2][r], acc[mi][3][r]));
      for (int o = 1; o < 16; o <<= 1) m = fmaxf(m, __shfl_xor(m, o));
      rmax[mi][r] = m;
    }
  if (fr == 0) {
#pragma unroll
    for (int mi = 0; mi < 4; ++mi)
#pragma unroll
      for (int r = 0; r < 4; ++r) redm[wv * 64 + mi * 16 + fg * 4 + r] = rmax[mi][r];
  }
  __syncthreads();
#pragma unroll
  for (int mi = 0; mi < 4; ++mi)
#pragma unroll
    for (int r = 0; r < 4; ++r) {
      const int row = mi * 16 + fg * 4 + r;
      rmax[mi][r] = fmaxf(fmaxf(redm[row], redm[64 + row]),
                          fmaxf(redm[128 + row], redm[192 + row]));
    }
#pragma unroll
  for (int mi = 0; mi < 4; ++mi)
#pragma unroll
    for (int r = 0; r < 4; ++r) {
      float s = 0.f;
#pragma unroll
      for (int ni = 0; ni < 4; ++ni) {
        float p = exp2f((acc[mi][ni][r] - rmax[mi][r]) * 1.4426950408889634f);
        acc[mi][ni][r] = p;
        s += p;
      }
      for (int o = 1; o < 16; o <<= 1) s += __shfl_xor(s, o);
      rnrm[mi][r] = s;
    }
  if (fr == 0) {
#pragma unroll
    for (int mi = 0; mi < 4; ++mi)
#pragma unroll
      for (int r = 0; r < 4; ++r) reds[wv * 64 + mi * 16 + fg * 4 + r] = rnrm[mi][r];
  }
  __syncthreads();
#pragma unroll
  for (int mi = 0; mi < 4; ++mi)
#pragma unroll
    for (int r = 0; r < 4; ++r) {
      const int row = mi * 16 + fg * 4 + r;
      rnrm[mi][r] = 1.f / (reds[row] + reds[64 + row] + reds[128 + row] + reds[192 + row]);
    }
#pragma unroll
  for (int mi = 0; mi < 4; ++mi)
#pragma unroll
    for (int ni = 0; ni < 4; ++ni)
#pragma unroll
      for (int r = 0; r < 4; ++r)
        lP[(mi * 16 + fg * 4 + r) * 264 + wv * 64 + ni * 16 + fr] =
            f2bf(acc[mi][ni][r] * rnrm[mi][r]);
  __syncthreads();  // lP ready; redm/reds region freed for lVt

  // ---- phase 3: O = P V, n-chunks of 256 cols, k(x)-tiles of 32
#pragma unroll 1
  for (int nc = 0; nc < 4; ++nc) {
    f32x4 oacc[4][4];
#pragma unroll
    for (int i = 0; i < 4; ++i)
#pragma unroll
      for (int j = 0; j < 4; ++j) oacc[i][j] = fz;
#pragma unroll 1
    for (int xt = 0; xt < 8; ++xt) {
      // stage V^T tile: [32 x][256 n] -> lVt[n][40] (x at 0..31, pad to 40)
#pragma unroll
      for (int it = 0; it < 4; ++it) {
        const int id = it * 256 + tid;
        const int xl = id & 31, ng = id >> 5;
        const int d = nc * 256 + ng * 8;
        const u16* g = qkv + qbase +
                       (size_t)((xt * 32 + xl) * 16 + (d >> 6)) * 3072 + 2048 +
                       h * 64 + (d & 63);
        s16x8 v = *(const s16x8*)g;
#pragma unroll
        for (int i = 0; i < 8; ++i) lVt[(ng * 8 + i) * 40 + xl] = (u16)v[i];
      }
      __syncthreads();
      s16x8 pa[4];
#pragma unroll
      for (int mi = 0; mi < 4; ++mi)
        pa[mi] = *(const s16x8*)(lP + (mi * 16 + fr) * 264 + xt * 32 + fg * 8);
#pragma unroll
      for (int ni = 0; ni < 4; ++ni) {
        s16x8 vb = *(const s16x8*)(lVt + (wv * 64 + ni * 16 + fr) * 40 + fg * 8);
#pragma unroll
        for (int mi = 0; mi < 4; ++mi)
          oacc[mi][ni] = MFMA_BF16(pa[mi], vb, oacc[mi][ni]);
      }
      __syncthreads();
    }
    // store O chunk -> attn_out token layout [B,N,H*hd]
#pragma unroll
    for (int mi = 0; mi < 4; ++mi)
#pragma unroll
      for (int ni = 0; ni < 4; ++ni) {
        const int row = mi * 16 + fg * 4;
        const int d = nc * 256 + wv * 64 + ni * 16 + fr;
        const int p = d >> 6, e = d & 63;
        const size_t base =
            (size_t)(b * 4096 + (qb * 64 + row) * 16 + p) * 1024 + h * 64 + e;
#pragma unroll
        for (int r = 0; r < 4; ++r)
          attn[base + (size_t)r * 16 * 1024] = f2bf(oacc[mi][ni][r]);
      }
  }
}

// ---------------------------------------------------------------------------
extern "C" void kernel_launch(void* const* d_in, const int* in_sizes, int n_in,
                              void* d_out, int out_size, void* d_ws, size_t ws_size,
                              hipStream_t stream) {
  (void)in_sizes; (void)n_in; (void)out_size; (void)ws_size;
  const float* x = (const float*)d_in[0];      // [16384,1024] f32
  const float* wqkv = (const float*)d_in[1];   // [3072,1024] f32
  const float* wproj = (const float*)d_in[2];  // [1024,1024] f32
  float* out = (float*)d_out;                  // [16384,1024] f32

  char* ws = (char*)d_ws;
  u16* qkv = (u16*)ws;                          // [16384,3072] bf16 (100.7 MB)
  u16* xbf = (u16*)(ws + 100663296);            // [16384,1024] bf16 (33.6 MB)
  u16* attn = xbf;                              // reuse: xbf dead after gemm1
  u16* wqkvb = (u16*)(ws + 134217728);          // [3072,1024] bf16 (6.3 MB)
  u16* wprojb = (u16*)(ws + 140509184);         // [1024,1024] bf16 (2.1 MB)

  cvt_bf16<<<2048, 256, 0, stream>>>(x, xbf, 16777216 / 8);
  cvt_bf16<<<1536, 256, 0, stream>>>(wqkv, wqkvb, 3145728 / 8);
  cvt_bf16<<<512, 256, 0, stream>>>(wproj, wprojb, 1048576 / 8);

  gemm256<true, false, 12><<<768, 512, 0, stream>>>(xbf, wqkvb, qkv);
  attn_win<<<256, 256, 0, stream>>>(qkv, attn);
  gemm256<false, true, 4><<<256, 512, 0, stream>>>(attn, wprojb, out);
}